// Round 7
// baseline (1489.293 us; speedup 1.0000x reference)
//
#include <hip/hip_runtime.h>
#include <math.h>

#define EPSV 1e-4f
#define NSWEEP 10
#define NRT (99 * NSWEEP)
#define SKIPTH 1e-9f

// ---------- Kernel A: W = W1 @ W2 (400x200 @ 200x100 -> 400x100) ----------
__global__ __launch_bounds__(256) void kA(const float* __restrict__ W1,
                                          const float* __restrict__ W2,
                                          float* __restrict__ W) {
  int e = blockIdx.x * 256 + threadIdx.x;
  if (e >= 400 * 100) return;
  int i = e / 100, j = e - (e / 100) * 100;
  float s = 0.f;
#pragma unroll 4
  for (int k = 0; k < 200; ++k) s += W1[i * 200 + k] * W2[k * 100 + j];
  W[e] = s;
}

// ---------- Kernel B: Y[b] = x[b] @ W  (400x400 @ 400x100) ----------
__global__ __launch_bounds__(256) void kB(const float* __restrict__ x,
                                          const float* __restrict__ W,
                                          float* __restrict__ Y) {
  __shared__ float xs[16][41];
  __shared__ float ws[40][104];
  const int b = blockIdx.y, rt = blockIdx.x;
  const int tid = threadIdx.x;
  const int tc = tid & 31, tr = tid >> 5;
  const float* xb = x + (size_t)b * 160000 + (size_t)rt * 16 * 400;
  float acc[2][4] = {{0.f, 0.f, 0.f, 0.f}, {0.f, 0.f, 0.f, 0.f}};
  for (int k0 = 0; k0 < 400; k0 += 40) {
    for (int e = tid; e < 640; e += 256) {
      int r = e / 40, kk = e - r * 40;
      xs[r][kk] = xb[r * 400 + k0 + kk];
    }
    for (int e = tid; e < 4000; e += 256) {
      int kk = e / 100, j = e - kk * 100;
      ws[kk][j] = W[(k0 + kk) * 100 + j];
    }
    __syncthreads();
#pragma unroll 8
    for (int kk = 0; kk < 40; ++kk) {
      float a0 = xs[tr][kk], a1 = xs[tr + 8][kk];
      float b0 = ws[kk][tc], b1 = ws[kk][tc + 32], b2 = ws[kk][tc + 64];
      float b3 = (tc + 96 < 100) ? ws[kk][tc + 96] : 0.f;
      acc[0][0] += a0 * b0; acc[0][1] += a0 * b1; acc[0][2] += a0 * b2; acc[0][3] += a0 * b3;
      acc[1][0] += a1 * b0; acc[1][1] += a1 * b1; acc[1][2] += a1 * b2; acc[1][3] += a1 * b3;
    }
    __syncthreads();
  }
  float* Yb = Y + (size_t)b * 40000 + (size_t)rt * 1600;
#pragma unroll
  for (int rr = 0; rr < 2; ++rr) {
    int r = tr + 8 * rr;
#pragma unroll
    for (int u = 0; u < 4; ++u) {
      int c = tc + 32 * u;
      if (c < 100) Yb[r * 100 + c] = acc[rr][u];
    }
  }
}

// flat triu index (n=100) -> row (one-off use in symmetrize)
__device__ __forceinline__ int triu_row(int e) {
  int i = (int)((201.0f - sqrtf(40401.0f - 8.0f * (float)e)) * 0.5f);
  if (i < 0) i = 0;
  if (i > 99) i = 99;
  while (i > 0 && (201 * i - i * i) > 2 * e) --i;
  while ((201 * (i + 1) - (i + 1) * (i + 1)) <= 2 * e) ++i;
  return i;
}

// ---------- Kernel C: M = W^T Y_b ; logm via ONE-SIDED Jacobi (fused, memoized) ----------
__global__ __launch_bounds__(1024) void kC(const float* __restrict__ W,
                                           const float* __restrict__ Y,
                                           const float* __restrict__ Wc,
                                           const float* __restrict__ bcv,
                                           float* __restrict__ out) {
  __shared__ float B[10000];       // column-major: column p at B + p*100
  __shared__ float stage[8320];    // GEMM staging; later Hf[5050]
  __shared__ float nrm[100];       // maintained squared column norms
  __shared__ float sfin[100];
  __shared__ float red[16][12];
  __shared__ unsigned int ver[100];    // per-column rotation counters
  __shared__ unsigned int memo[10000]; // per-pair clean-version key (mn*100+mx)
  __shared__ int rotflag[50];
  __shared__ int brk;

  const int b = blockIdx.x, tid = threadIdx.x;
  const int q4 = tid & 31;
  const int r32 = tid >> 5;
  const int g = tid >> 4, lane = tid & 15;  // 64 groups of 16 (wave-aligned)

  // ---- M = W^T @ Y_b  into B ----
  {
    float* Wst = stage;          // [40][104]
    float* Yst = stage + 4160;   // [40][104]
    const float* Yb = Y + (size_t)b * 40000;
    float acc[4][4];
#pragma unroll
    for (int m = 0; m < 4; ++m) acc[m][0] = acc[m][1] = acc[m][2] = acc[m][3] = 0.f;
    for (int k0 = 0; k0 < 400; k0 += 40) {
      for (int e = tid; e < 4000; e += 1024) {
        int kk = e / 100, j = e - kk * 100;
        Wst[kk * 104 + j] = W[(k0 + kk) * 100 + j];
        Yst[kk * 104 + j] = Yb[(k0 + kk) * 100 + j];
      }
      __syncthreads();
      for (int kk = 0; kk < 40; ++kk) {
        float y0 = Yst[kk * 104 + q4], y1 = Yst[kk * 104 + q4 + 32], y2 = Yst[kk * 104 + q4 + 64];
        float y3 = (q4 + 96 < 100) ? Yst[kk * 104 + q4 + 96] : 0.f;
#pragma unroll
        for (int m = 0; m < 4; ++m) {
          int p = r32 + 32 * m;
          if (p < 100) {
            float w = Wst[kk * 104 + p];
            acc[m][0] += w * y0; acc[m][1] += w * y1; acc[m][2] += w * y2; acc[m][3] += w * y3;
          }
        }
      }
      __syncthreads();
    }
#pragma unroll
    for (int m = 0; m < 4; ++m) {
      int p = r32 + 32 * m;
      if (p < 100) {
        B[p * 100 + q4] = acc[m][0];
        B[p * 100 + q4 + 32] = acc[m][1];
        B[p * 100 + q4 + 64] = acc[m][2];
        if (q4 + 96 < 100) B[p * 100 + q4 + 96] = acc[m][3];
      }
    }
  }
  // init memo/ver/flags
  for (int e = tid; e < 10000; e += 1024) memo[e] = 0xFFFFFFFFu;
  if (tid < 100) ver[tid] = 0u;
  if (tid < 50) rotflag[tid] = 0;
  __syncthreads();
  // symmetrize both triangles
  for (int e = tid; e < 5050; e += 1024) {
    int i = triu_row(e);
    int j = i + (e - ((201 * i - i * i) >> 1));
    float av = 0.5f * (B[i * 100 + j] + B[j * 100 + i]);
    B[i * 100 + j] = av;
    B[j * 100 + i] = av;
  }
  __syncthreads();
  // initial squared norms (group g covers columns g, g+64)
  for (int col = g; col < 100; col += 64) {
    const float* bp = B + col * 100;
    float4 a4 = *(const float4*)(bp + 4 * lane);
    float n = a4.x * a4.x + a4.y * a4.y + a4.z * a4.z + a4.w * a4.w;
    if (lane < 9) {
      float4 a8 = *(const float4*)(bp + 64 + 4 * lane);
      n += a8.x * a8.x + a8.y * a8.y + a8.z * a8.z + a8.w * a8.w;
    }
#pragma unroll
    for (int off = 1; off <= 8; off <<= 1) n += __shfl_xor(n, off);
    if (lane == 0) nrm[col] = n;
  }
  __syncthreads();

  // ---- one-sided cyclic Jacobi: fused dot+rotate, memoized pair skipping ----
  for (int r = 0; r < NRT; ++r) {
    const int rr = r % 99;
    if (g < 50) {
      int p, q;
      if (g == 0) { p = 99; q = rr; }
      else {
        p = rr + g; if (p >= 99) p -= 99;
        q = rr - g; if (q < 0) q += 99;
      }
      const int mn = (p < q) ? p : q, mx = (p < q) ? q : p;
      const int pqi = mn * 100 + mx;
      const unsigned int key = (ver[mn] << 16) | ver[mx];
      if (memo[pqi] != key) {  // columns changed since last clean check
        float* bp = B + p * 100;
        float* bq = B + q * 100;
        float4 a4 = *(const float4*)(bp + 4 * lane);
        float4 b4 = *(const float4*)(bq + 4 * lane);
        float4 a8 = make_float4(0.f, 0.f, 0.f, 0.f), b8 = a8;
        float d = a4.x * b4.x + a4.y * b4.y + a4.z * b4.z + a4.w * b4.w;
        if (lane < 9) {
          a8 = *(const float4*)(bp + 64 + 4 * lane);
          b8 = *(const float4*)(bq + 64 + 4 * lane);
          d += a8.x * b8.x + a8.y * b8.y + a8.z * b8.z + a8.w * b8.w;
        }
#pragma unroll
        for (int off = 1; off <= 8; off <<= 1) d += __shfl_xor(d, off);
        float pn = nrm[p], qn = nrm[q];
        if (d * d > SKIPTH * pn * qn + 1e-30f) {  // group-uniform branch
          float tau = (qn - pn) / (2.f * d);
          float t = copysignf(1.f, tau) / (fabsf(tau) + sqrtf(1.f + tau * tau));
          float c = 1.f / sqrtf(1.f + t * t);
          float s = t * c;
          float4 n4, m4;
          n4.x = c * a4.x - s * b4.x; n4.y = c * a4.y - s * b4.y;
          n4.z = c * a4.z - s * b4.z; n4.w = c * a4.w - s * b4.w;
          m4.x = s * a4.x + c * b4.x; m4.y = s * a4.y + c * b4.y;
          m4.z = s * a4.z + c * b4.z; m4.w = s * a4.w + c * b4.w;
          *(float4*)(bp + 4 * lane) = n4;
          *(float4*)(bq + 4 * lane) = m4;
          if (lane < 9) {
            n4.x = c * a8.x - s * b8.x; n4.y = c * a8.y - s * b8.y;
            n4.z = c * a8.z - s * b8.z; n4.w = c * a8.w - s * b8.w;
            m4.x = s * a8.x + c * b8.x; m4.y = s * a8.y + c * b8.y;
            m4.z = s * a8.z + c * b8.z; m4.w = s * a8.w + c * b8.w;
            *(float4*)(bp + 64 + 4 * lane) = n4;
            *(float4*)(bq + 64 + 4 * lane) = m4;
          }
          if (lane == 0) {
            nrm[p] = pn - t * d;   // exact Jacobi diagonal update
            nrm[q] = qn + t * d;
            unsigned int vmn = (key >> 16) + 1u, vmx = (key & 0xFFFFu) + 1u;
            ver[mn] = vmn; ver[mx] = vmx;
            memo[pqi] = (vmn << 16) | vmx;  // post-rotation d ~ roundoff: clean
            rotflag[g] = 1;
          }
        } else {
          if (lane == 0) memo[pqi] = key;   // clean at these versions
        }
      }
    }
    __syncthreads();
    if (rr == 98) {  // sweep end: OR the sticky flags, clear, maybe break
      if (tid < 64) {
        int v = (tid < 50) ? rotflag[tid] : 0;
#pragma unroll
        for (int off = 32; off > 0; off >>= 1) v += __shfl_xor(v, off);
        if (tid == 0) brk = (v == 0) ? 1 : 0;
        if (tid < 50) rotflag[tid] = 0;
      }
      __syncthreads();
      if (brk) break;
    }
  }

  // ---- exact final scales: sfin[p] = log(max(||b_p||,EPSV)) / ||b_p||^2 ----
  for (int col = g; col < 100; col += 64) {
    const float* bp = B + col * 100;
    float4 a4 = *(const float4*)(bp + 4 * lane);
    float n = a4.x * a4.x + a4.y * a4.y + a4.z * a4.z + a4.w * a4.w;
    if (lane < 9) {
      float4 a8 = *(const float4*)(bp + 64 + 4 * lane);
      n += a8.x * a8.x + a8.y * a8.y + a8.z * a8.z + a8.w * a8.w;
    }
#pragma unroll
    for (int off = 1; off <= 8; off <<= 1) n += __shfl_xor(n, off);
    if (lane == 0) sfin[col] = logf(fmaxf(sqrtf(n), EPSV)) / n;
  }
  __syncthreads();

  // ---- Hf (triu flat) = sum_p sfin[p] * b_p b_p^T ----
  float* Hf = stage;
  {
    float hacc[4][4];
#pragma unroll
    for (int m = 0; m < 4; ++m) hacc[m][0] = hacc[m][1] = hacc[m][2] = hacc[m][3] = 0.f;
    for (int p = 0; p < 100; ++p) {
      float l = sfin[p];
      const float* vr = B + p * 100;
      float vj0 = vr[q4], vj1 = vr[q4 + 32], vj2 = vr[q4 + 64];
      float vj3 = (q4 + 96 < 100) ? vr[q4 + 96] : 0.f;
#pragma unroll
      for (int m = 0; m < 4; ++m) {
        int i = r32 + 32 * m;
        if (i < 100) {
          float vil = vr[i] * l;
          hacc[m][0] += vil * vj0; hacc[m][1] += vil * vj1;
          hacc[m][2] += vil * vj2; hacc[m][3] += vil * vj3;
        }
      }
    }
    __syncthreads();
#pragma unroll
    for (int m = 0; m < 4; ++m) {
      int i = r32 + 32 * m;
      if (i >= 100) continue;
#pragma unroll
      for (int n = 0; n < 4; ++n) {
        int j = q4 + 32 * n;
        if (j < 100 && i <= j) Hf[((201 * i - i * i) >> 1) + (j - i)] = hacc[m][n];
      }
    }
  }
  __syncthreads();

  // ---- classifier ----
  float accc[10];
#pragma unroll
  for (int c = 0; c < 10; ++c) accc[c] = 0.f;
  for (int e = tid; e < 5050; e += 1024) {
    float h = Hf[e];
#pragma unroll
    for (int c = 0; c < 10; ++c) accc[c] += h * Wc[c * 5050 + e];
  }
  const int lane64 = tid & 63, wv = tid >> 6;
#pragma unroll
  for (int c = 0; c < 10; ++c) {
    float v = accc[c];
#pragma unroll
    for (int off = 32; off > 0; off >>= 1) v += __shfl_down(v, off);
    if (lane64 == 0) red[wv][c] = v;
  }
  __syncthreads();
  if (tid < 10) {
    float s = bcv[tid];
#pragma unroll
    for (int w = 0; w < 16; ++w) s += red[w][tid];
    out[b * 10 + tid] = s;
  }
}

extern "C" void kernel_launch(void* const* d_in, const int* in_sizes, int n_in,
                              void* d_out, int out_size, void* d_ws, size_t ws_size,
                              hipStream_t stream) {
  const float* x = (const float*)d_in[0];
  const float* W1 = (const float*)d_in[1];
  const float* W2 = (const float*)d_in[2];
  const float* Wc = (const float*)d_in[3];
  const float* bc = (const float*)d_in[4];
  float* out = (float*)d_out;

  float* W = (float*)d_ws;        // 400*100 floats
  float* Y = W + 40000;           // 256*400*100 floats (~41 MB)

  kA<<<157, 256, 0, stream>>>(W1, W2, W);
  kB<<<dim3(25, 256), 256, 0, stream>>>(x, W, Y);
  kC<<<256, 1024, 0, stream>>>(W, Y, Wc, bc, out);
}

// Round 8
// 1303.329 us; speedup vs baseline: 1.1427x; 1.1427x over previous
//
#include <hip/hip_runtime.h>
#include <math.h>

#define EPSV 1e-4f
#define NSWEEP 10
#define NRT (99 * NSWEEP)
#define SKIPTH 1e-9f

// ---------- 16-lane all-reduce sum on the VALU (DPP), no LDS pipe ----------
template <int CTRL>
__device__ __forceinline__ float dppadd(float x) {
  int y = __builtin_amdgcn_update_dpp(0, __float_as_int(x), CTRL, 0xF, 0xF, false);
  return x + __int_as_float(y);
}
__device__ __forceinline__ float sum16(float x) {
  x = dppadd<0xB1>(x);   // quad_perm [1,0,3,2]  == xor 1
  x = dppadd<0x4E>(x);   // quad_perm [2,3,0,1]  == xor 2
  x = dppadd<0x124>(x);  // row_ror:4  (quad i += quad i+1)
  x = dppadd<0x128>(x);  // row_ror:8  (+= opposite half)
  return x;
}

// ---------- Kernel A: W = W1 @ W2 (400x200 @ 200x100 -> 400x100) ----------
__global__ __launch_bounds__(256) void kA(const float* __restrict__ W1,
                                          const float* __restrict__ W2,
                                          float* __restrict__ W) {
  int e = blockIdx.x * 256 + threadIdx.x;
  if (e >= 400 * 100) return;
  int i = e / 100, j = e - (e / 100) * 100;
  float s = 0.f;
#pragma unroll 4
  for (int k = 0; k < 200; ++k) s += W1[i * 200 + k] * W2[k * 100 + j];
  W[e] = s;
}

// ---------- Kernel B: Y[b] = x[b] @ W  (400x400 @ 400x100) ----------
__global__ __launch_bounds__(256) void kB(const float* __restrict__ x,
                                          const float* __restrict__ W,
                                          float* __restrict__ Y) {
  __shared__ float xs[16][41];
  __shared__ float ws[40][104];
  const int b = blockIdx.y, rt = blockIdx.x;
  const int tid = threadIdx.x;
  const int tc = tid & 31, tr = tid >> 5;
  const float* xb = x + (size_t)b * 160000 + (size_t)rt * 16 * 400;
  float acc[2][4] = {{0.f, 0.f, 0.f, 0.f}, {0.f, 0.f, 0.f, 0.f}};
  for (int k0 = 0; k0 < 400; k0 += 40) {
    for (int e = tid; e < 640; e += 256) {
      int r = e / 40, kk = e - r * 40;
      xs[r][kk] = xb[r * 400 + k0 + kk];
    }
    for (int e = tid; e < 4000; e += 256) {
      int kk = e / 100, j = e - kk * 100;
      ws[kk][j] = W[(k0 + kk) * 100 + j];
    }
    __syncthreads();
#pragma unroll 8
    for (int kk = 0; kk < 40; ++kk) {
      float a0 = xs[tr][kk], a1 = xs[tr + 8][kk];
      float b0 = ws[kk][tc], b1 = ws[kk][tc + 32], b2 = ws[kk][tc + 64];
      float b3 = (tc + 96 < 100) ? ws[kk][tc + 96] : 0.f;
      acc[0][0] += a0 * b0; acc[0][1] += a0 * b1; acc[0][2] += a0 * b2; acc[0][3] += a0 * b3;
      acc[1][0] += a1 * b0; acc[1][1] += a1 * b1; acc[1][2] += a1 * b2; acc[1][3] += a1 * b3;
    }
    __syncthreads();
  }
  float* Yb = Y + (size_t)b * 40000 + (size_t)rt * 1600;
#pragma unroll
  for (int rr = 0; rr < 2; ++rr) {
    int r = tr + 8 * rr;
#pragma unroll
    for (int u = 0; u < 4; ++u) {
      int c = tc + 32 * u;
      if (c < 100) Yb[r * 100 + c] = acc[rr][u];
    }
  }
}

// flat triu index (n=100) -> row (one-off use in symmetrize)
__device__ __forceinline__ int triu_row(int e) {
  int i = (int)((201.0f - sqrtf(40401.0f - 8.0f * (float)e)) * 0.5f);
  if (i < 0) i = 0;
  if (i > 99) i = 99;
  while (i > 0 && (201 * i - i * i) > 2 * e) --i;
  while ((201 * (i + 1) - (i + 1) * (i + 1)) <= 2 * e) ++i;
  return i;
}

// ---------- Kernel C: M = W^T Y_b ; logm via ONE-SIDED Jacobi (fused, DPP) ----------
__global__ __launch_bounds__(1024) void kC(const float* __restrict__ W,
                                           const float* __restrict__ Y,
                                           const float* __restrict__ Wc,
                                           const float* __restrict__ bcv,
                                           float* __restrict__ out) {
  __shared__ float B[10000];      // column-major: column p at B + p*100
  __shared__ float stage[8320];   // GEMM staging; later Hf[5050]
  __shared__ float nrm[100];      // maintained squared column norms
  __shared__ float sfin[100];
  __shared__ float red[16][12];
  __shared__ int rotflag[50];
  __shared__ int brk;

  const int b = blockIdx.x, tid = threadIdx.x;
  const int q4 = tid & 31;
  const int r32 = tid >> 5;
  const int g = tid >> 4, lane = tid & 15;  // 64 groups of 16 (wave-aligned)

  // ---- M = W^T @ Y_b  into B ----
  {
    float* Wst = stage;          // [40][104]
    float* Yst = stage + 4160;   // [40][104]
    const float* Yb = Y + (size_t)b * 40000;
    float acc[4][4];
#pragma unroll
    for (int m = 0; m < 4; ++m) acc[m][0] = acc[m][1] = acc[m][2] = acc[m][3] = 0.f;
    for (int k0 = 0; k0 < 400; k0 += 40) {
      for (int e = tid; e < 4000; e += 1024) {
        int kk = e / 100, j = e - kk * 100;
        Wst[kk * 104 + j] = W[(k0 + kk) * 100 + j];
        Yst[kk * 104 + j] = Yb[(k0 + kk) * 100 + j];
      }
      __syncthreads();
      for (int kk = 0; kk < 40; ++kk) {
        float y0 = Yst[kk * 104 + q4], y1 = Yst[kk * 104 + q4 + 32], y2 = Yst[kk * 104 + q4 + 64];
        float y3 = (q4 + 96 < 100) ? Yst[kk * 104 + q4 + 96] : 0.f;
#pragma unroll
        for (int m = 0; m < 4; ++m) {
          int p = r32 + 32 * m;
          if (p < 100) {
            float w = Wst[kk * 104 + p];
            acc[m][0] += w * y0; acc[m][1] += w * y1; acc[m][2] += w * y2; acc[m][3] += w * y3;
          }
        }
      }
      __syncthreads();
    }
#pragma unroll
    for (int m = 0; m < 4; ++m) {
      int p = r32 + 32 * m;
      if (p < 100) {
        B[p * 100 + q4] = acc[m][0];
        B[p * 100 + q4 + 32] = acc[m][1];
        B[p * 100 + q4 + 64] = acc[m][2];
        if (q4 + 96 < 100) B[p * 100 + q4 + 96] = acc[m][3];
      }
    }
  }
  if (tid < 50) rotflag[tid] = 0;
  __syncthreads();
  // symmetrize both triangles
  for (int e = tid; e < 5050; e += 1024) {
    int i = triu_row(e);
    int j = i + (e - ((201 * i - i * i) >> 1));
    float av = 0.5f * (B[i * 100 + j] + B[j * 100 + i]);
    B[i * 100 + j] = av;
    B[j * 100 + i] = av;
  }
  __syncthreads();
  // initial squared norms (group g covers columns g, g+64)
  for (int col = g; col < 100; col += 64) {
    const float* bp = B + col * 100;
    float4 a4 = *(const float4*)(bp + 4 * lane);
    float n = a4.x * a4.x + a4.y * a4.y + a4.z * a4.z + a4.w * a4.w;
    if (lane < 9) {
      float4 a8 = *(const float4*)(bp + 64 + 4 * lane);
      n += a8.x * a8.x + a8.y * a8.y + a8.z * a8.z + a8.w * a8.w;
    }
    n = sum16(n);
    if (lane == 0) nrm[col] = n;
  }
  __syncthreads();

  // ---- one-sided cyclic Jacobi: fused dot+rotate, DPP reduce, 1 barrier/round ----
  for (int r = 0; r < NRT; ++r) {
    const int rr = r % 99;
    if (g < 50) {
      int p, q;
      if (g == 0) { p = 99; q = rr; }
      else {
        p = rr + g; if (p >= 99) p -= 99;
        q = rr - g; if (q < 0) q += 99;
      }
      float* bp = B + p * 100;
      float* bq = B + q * 100;
      float4 a4 = *(const float4*)(bp + 4 * lane);
      float4 b4 = *(const float4*)(bq + 4 * lane);
      float4 a8 = make_float4(0.f, 0.f, 0.f, 0.f), b8 = a8;
      float d = a4.x * b4.x + a4.y * b4.y + a4.z * b4.z + a4.w * b4.w;
      if (lane < 9) {
        a8 = *(const float4*)(bp + 64 + 4 * lane);
        b8 = *(const float4*)(bq + 64 + 4 * lane);
        d += a8.x * b8.x + a8.y * b8.y + a8.z * b8.z + a8.w * b8.w;
      }
      d = sum16(d);  // VALU DPP all-reduce, off the LDS pipe
      float pn = nrm[p], qn = nrm[q];
      if (d * d > SKIPTH * pn * qn + 1e-30f) {  // group-uniform branch
        float tau = (qn - pn) / (2.f * d);
        float t = copysignf(1.f, tau) / (fabsf(tau) + sqrtf(1.f + tau * tau));
        float c = 1.f / sqrtf(1.f + t * t);
        float s = t * c;
        float4 n4, m4;
        n4.x = c * a4.x - s * b4.x; n4.y = c * a4.y - s * b4.y;
        n4.z = c * a4.z - s * b4.z; n4.w = c * a4.w - s * b4.w;
        m4.x = s * a4.x + c * b4.x; m4.y = s * a4.y + c * b4.y;
        m4.z = s * a4.z + c * b4.z; m4.w = s * a4.w + c * b4.w;
        *(float4*)(bp + 4 * lane) = n4;
        *(float4*)(bq + 4 * lane) = m4;
        if (lane < 9) {
          n4.x = c * a8.x - s * b8.x; n4.y = c * a8.y - s * b8.y;
          n4.z = c * a8.z - s * b8.z; n4.w = c * a8.w - s * b8.w;
          m4.x = s * a8.x + c * b8.x; m4.y = s * a8.y + c * b8.y;
          m4.z = s * a8.z + c * b8.z; m4.w = s * a8.w + c * b8.w;
          *(float4*)(bp + 64 + 4 * lane) = n4;
          *(float4*)(bq + 64 + 4 * lane) = m4;
        }
        if (lane == 0) {
          nrm[p] = pn - t * d;   // exact Jacobi diagonal update
          nrm[q] = qn + t * d;
          rotflag[g] = 1;        // sticky, no atomic
        }
      }
    }
    __syncthreads();
    if (rr == 98) {  // sweep end: OR the sticky flags, clear, maybe break
      if (tid < 64) {
        int v = (tid < 50) ? rotflag[tid] : 0;
#pragma unroll
        for (int off = 32; off > 0; off >>= 1) v += __shfl_xor(v, off);
        if (tid == 0) brk = (v == 0) ? 1 : 0;
        if (tid < 50) rotflag[tid] = 0;
      }
      __syncthreads();
      if (brk) break;
    }
  }

  // ---- exact final scales: sfin[p] = log(max(||b_p||,EPSV)) / ||b_p||^2 ----
  for (int col = g; col < 100; col += 64) {
    const float* bp = B + col * 100;
    float4 a4 = *(const float4*)(bp + 4 * lane);
    float n = a4.x * a4.x + a4.y * a4.y + a4.z * a4.z + a4.w * a4.w;
    if (lane < 9) {
      float4 a8 = *(const float4*)(bp + 64 + 4 * lane);
      n += a8.x * a8.x + a8.y * a8.y + a8.z * a8.z + a8.w * a8.w;
    }
    n = sum16(n);
    if (lane == 0) sfin[col] = logf(fmaxf(sqrtf(n), EPSV)) / n;
  }
  __syncthreads();

  // ---- Hf (triu flat) = sum_p sfin[p] * b_p b_p^T ----
  float* Hf = stage;
  {
    float hacc[4][4];
#pragma unroll
    for (int m = 0; m < 4; ++m) hacc[m][0] = hacc[m][1] = hacc[m][2] = hacc[m][3] = 0.f;
    for (int p = 0; p < 100; ++p) {
      float l = sfin[p];
      const float* vr = B + p * 100;
      float vj0 = vr[q4], vj1 = vr[q4 + 32], vj2 = vr[q4 + 64];
      float vj3 = (q4 + 96 < 100) ? vr[q4 + 96] : 0.f;
#pragma unroll
      for (int m = 0; m < 4; ++m) {
        int i = r32 + 32 * m;
        if (i < 100) {
          float vil = vr[i] * l;
          hacc[m][0] += vil * vj0; hacc[m][1] += vil * vj1;
          hacc[m][2] += vil * vj2; hacc[m][3] += vil * vj3;
        }
      }
    }
    __syncthreads();
#pragma unroll
    for (int m = 0; m < 4; ++m) {
      int i = r32 + 32 * m;
      if (i >= 100) continue;
#pragma unroll
      for (int n = 0; n < 4; ++n) {
        int j = q4 + 32 * n;
        if (j < 100 && i <= j) Hf[((201 * i - i * i) >> 1) + (j - i)] = hacc[m][n];
      }
    }
  }
  __syncthreads();

  // ---- classifier ----
  float accc[10];
#pragma unroll
  for (int c = 0; c < 10; ++c) accc[c] = 0.f;
  for (int e = tid; e < 5050; e += 1024) {
    float h = Hf[e];
#pragma unroll
    for (int c = 0; c < 10; ++c) accc[c] += h * Wc[c * 5050 + e];
  }
  const int lane64 = tid & 63, wv = tid >> 6;
#pragma unroll
  for (int c = 0; c < 10; ++c) {
    float v = accc[c];
#pragma unroll
    for (int off = 32; off > 0; off >>= 1) v += __shfl_down(v, off);
    if (lane64 == 0) red[wv][c] = v;
  }
  __syncthreads();
  if (tid < 10) {
    float s = bcv[tid];
#pragma unroll
    for (int w = 0; w < 16; ++w) s += red[w][tid];
    out[b * 10 + tid] = s;
  }
}

extern "C" void kernel_launch(void* const* d_in, const int* in_sizes, int n_in,
                              void* d_out, int out_size, void* d_ws, size_t ws_size,
                              hipStream_t stream) {
  const float* x = (const float*)d_in[0];
  const float* W1 = (const float*)d_in[1];
  const float* W2 = (const float*)d_in[2];
  const float* Wc = (const float*)d_in[3];
  const float* bc = (const float*)d_in[4];
  float* out = (float*)d_out;

  float* W = (float*)d_ws;        // 400*100 floats
  float* Y = W + 40000;           // 256*400*100 floats (~41 MB)

  kA<<<157, 256, 0, stream>>>(W1, W2, W);
  kB<<<dim3(25, 256), 256, 0, stream>>>(x, W, Y);
  kC<<<256, 1024, 0, stream>>>(W, Y, Wc, bc, out);
}